// Round 7
// baseline (73.286 us; speedup 1.0000x reference)
//
#include <hip/hip_runtime.h>

#define TPB 512
#define RPB 16                          // rows per tile
#define SEQ_L 2048
#define CHUNK 512                       // j-chunk width = TPB
#define NCH (SEQ_L / CHUNK)             // 4
#define NBATCH 8
#define NPAIR 64                        // tile pairs (t, 127-t)
#define NBLOCKS (NBATCH * NPAIR)        // 512
#define NWAVE (TPB / 64)                // 8

static constexpr float kBondTol  = 0.4f;
static constexpr float kClashTol = 1.5f;
static constexpr float kIdeal    = 3.8f;
static constexpr float kEps      = 1e-8f;
static constexpr float kThresh2  = 2.25f;   // 1.5^2: d2 >= this -> relu == 0

__device__ __forceinline__ float wred(float v) {
#pragma unroll
  for (int o = 32; o > 0; o >>= 1) v += __shfl_down(v, o, 64);
  return v;
}

// Every block: tiles {g, 127-g}. k0(g) + k0(127-g) = 3 (512-chunks), so each
// block runs exactly 2 boundary + 3 full passes — identical work for ALL
// blocks, no dependence on block->CU scheduling.
__global__ __launch_bounds__(TPB, 4) void viol_main(
    const float* __restrict__ pos,    // [B, L, 3]
    const float* __restrict__ mask,   // [B, L]
    float4* __restrict__ partial) {   // [NBLOCKS]: (bv, bm, 2*cv_half, pm)
  __shared__ float4 s[SEQ_L];         // 32 KB; [jbase, 2048) valid
  __shared__ float  redm[NWAVE];
  __shared__ float  red4[NWAVE][4];

  const int b  = blockIdx.x & 7;      // batch -> XCD-pinned
  const int g  = blockIdx.x >> 3;     // pair index 0..63
  const int i0A = g << 4;             // low tile rows
  const int i0B = (127 - g) << 4;     // complement tile rows
  const int k0A = i0A >> 9;           // 0..1
  const int k0B = i0B >> 9;           // 2..3 (k0A + k0B == 3)
  const int jbase = k0A << 9;

  const float* pb = pos  + (size_t)b * SEQ_L * 3;
  const float* mb = mask + (size_t)b * SEQ_L;

  // ---- full-batch mask sum from global (L2-hit) ----
  float mpart = 0.f;
#pragma unroll
  for (int it = 0; it < NCH; ++it) mpart += mb[threadIdx.x + (it << 9)];
  mpart = wred(mpart);

  // ---- stage [jbase, 2048) once; both tiles read only j >= jbase ----
  for (int idx = jbase + (int)threadIdx.x; idx < SEQ_L; idx += TPB) {
    float x = pb[3 * idx + 0];
    float y = pb[3 * idx + 1];
    float z = pb[3 * idx + 2];
    s[idx] = make_float4(x, y, z, mb[idx]);
  }

  const int wid  = threadIdx.x >> 6;
  const int lane = threadIdx.x & 63;
  if (lane == 0) redm[wid] = mpart;
  __syncthreads();
  float msum = 0.f;
#pragma unroll
  for (int w = 0; w < NWAVE; ++w) msum += redm[w];

  float cv = 0.f, pm = 0.f, bv = 0.f, bm = 0.f;

  // ---- two tiles, sequential, register row-tile each ----
#pragma unroll
  for (int tt = 0; tt < 2; ++tt) {
    const int i0 = tt ? i0B : i0A;
    const int k0 = tt ? k0B : k0A;

    float px[RPB], py[RPB], pz[RPB], pw[RPB], accr[RPB];
#pragma unroll
    for (int q = 0; q < RPB; ++q) {
      float4 p = s[i0 + q];           // broadcast read (conflict-free)
      px[q] = p.x; py[q] = p.y; pz[q] = p.z; pw[q] = p.w;
      accr[q] = 0.f;
    }

    // boundary chunk (contains this tile's diagonal): masked, always-sqrt
    {
      const int j = (int)threadIdx.x + (k0 << 9);
      const float4 pj = s[j];
#pragma unroll
      for (int q = 0; q < RPB; ++q) {
        const int i = i0 + q;
        float dx = pj.x - px[q];
        float dy = pj.y - py[q];
        float dz = pj.z - pz[q];
        float d2 = fmaf(dx, dx, fmaf(dy, dy, dz * dz));
        float dist = __builtin_amdgcn_sqrtf(d2 + kEps);
        float mw = (j > i) ? pj.w : 0.f;        // strict upper triangle
        accr[q] = fmaf(fmaxf(kClashTol - dist, 0.f), mw, accr[q]);
      }
    }

    // full chunks above the tile: d2-only + wave-uniform sqrt skip
    for (int k = k0 + 1; k < NCH; ++k) {
      float4 pj = s[threadIdx.x + (k << 9)];
      float d2r[RPB];
#pragma unroll
      for (int q = 0; q < RPB; ++q) {
        float dx = pj.x - px[q];
        float dy = pj.y - py[q];
        float dz = pj.z - pz[q];
        d2r[q] = fmaf(dx, dx, fmaf(dy, dy, dz * dz));
      }
      float mv = d2r[0];
#pragma unroll
      for (int q = 1; q < RPB; ++q) mv = fminf(mv, d2r[q]); // fuses to min3
      if (__ballot(mv < kThresh2) != 0ull) {
#pragma unroll
        for (int q = 0; q < RPB; ++q) {
          float dist = __builtin_amdgcn_sqrtf(d2r[q] + kEps);
          accr[q] = fmaf(fmaxf(kClashTol - dist, 0.f), pj.w, accr[q]);
        }
      }
    }

#pragma unroll
    for (int q = 0; q < RPB; ++q) cv = fmaf(pw[q], accr[q], cv);
  }

  // ---- near-diagonal correction (i < j <= i+2) + bond + analytic pm ----
  // 32 rows per block (2 tiles x 16): threads 0..31 (single wave).
  if (threadIdx.x < 32) {
    const int i = ((threadIdx.x & 16) ? i0B : i0A) + (int)(threadIdx.x & 15);
    const float4 pi = s[i];           // i >= jbase: staged
    float nv = 0.f;
    const int jhi = (i + 2 > SEQ_L - 1) ? SEQ_L - 1 : i + 2;
    for (int j = i + 1; j <= jhi; ++j) {        // j > i >= jbase: staged
      float4 pj = s[j];
      float dx = pj.x - pi.x;
      float dy = pj.y - pi.y;
      float dz = pj.z - pi.z;
      float dist = __builtin_amdgcn_sqrtf(dx * dx + dy * dy + dz * dz + kEps);
      nv += fmaxf(kClashTol - dist, 0.f) * pj.w;
    }
    cv -= pi.w * nv;

    float nm = 0.f;                   // |i-j|<=2 window incl. j==i, from global
    const int jlo = (i - 2 < 0) ? 0 : i - 2;
    for (int j = jlo; j <= jhi; ++j) nm += mb[j];
    pm += pi.w * (msum - nm);         // analytic pair-mask row sum

    if (i < SEQ_L - 1) {
      const float4 pj = s[i + 1];
      float dx = pj.x - pi.x;
      float dy = pj.y - pi.y;
      float dz = pj.z - pi.z;
      float dist = __builtin_amdgcn_sqrtf(dx * dx + dy * dy + dz * dz + kEps);
      float viol = fmaxf(fabsf(dist - kIdeal) - kBondTol, 0.f);
      bv += viol * pi.w * pj.w;
      bm += pi.w * pj.w;
    }
  }

  // ---- block reduction -> ONE plain float4 store per block (no atomics) ----
  bv = wred(bv); bm = wred(bm); cv = wred(cv); pm = wred(pm);
  if (lane == 0) {
    red4[wid][0] = bv; red4[wid][1] = bm;
    red4[wid][2] = cv; red4[wid][3] = pm;
  }
  __syncthreads();
  if (threadIdx.x == 0) {
    float tbv = 0.f, tbm = 0.f, tcv = 0.f, tpm = 0.f;
#pragma unroll
    for (int w = 0; w < NWAVE; ++w) {
      tbv += red4[w][0]; tbm += red4[w][1];
      tcv += red4[w][2]; tpm += red4[w][3];
    }
    // x2: upper triangle -> full ordered sum
    partial[blockIdx.x] = make_float4(tbv, tbm, 2.f * tcv, tpm);
  }
}

__global__ __launch_bounds__(256) void viol_reduce(
    const float4* __restrict__ partial, float* __restrict__ out) {
  __shared__ float red4[4][4];
  float bv = 0.f, bm = 0.f, cv = 0.f, pm = 0.f;
#pragma unroll
  for (int i = threadIdx.x; i < NBLOCKS; i += 256) {
    float4 p = partial[i];
    bv += p.x; bm += p.y; cv += p.z; pm += p.w;
  }
  bv = wred(bv); bm = wred(bm); cv = wred(cv); pm = wred(pm);
  const int wid  = threadIdx.x >> 6;
  const int lane = threadIdx.x & 63;
  if (lane == 0) {
    red4[wid][0] = bv; red4[wid][1] = bm;
    red4[wid][2] = cv; red4[wid][3] = pm;
  }
  __syncthreads();
  if (threadIdx.x == 0) {
    float tbv = 0.f, tbm = 0.f, tcv = 0.f, tpm = 0.f;
#pragma unroll
    for (int w = 0; w < 4; ++w) {
      tbv += red4[w][0]; tbm += red4[w][1];
      tcv += red4[w][2]; tpm += red4[w][3];
    }
    float bond  = tbv / (tbm + kEps);
    float clash = tcv / (tpm + kEps);
    out[0] = bond;
    out[1] = clash;
    out[2] = bond + clash;
  }
}

extern "C" void kernel_launch(void* const* d_in, const int* in_sizes, int n_in,
                              void* d_out, int out_size, void* d_ws, size_t ws_size,
                              hipStream_t stream) {
  const float* pos  = (const float*)d_in[0];
  const float* mask = (const float*)d_in[1];
  float* out = (float*)d_out;
  float4* partial = (float4*)d_ws;   // 512 * 16 B = 8 KB scratch

  viol_main<<<dim3(NBLOCKS), dim3(TPB), 0, stream>>>(pos, mask, partial);
  viol_reduce<<<dim3(1), dim3(256), 0, stream>>>(partial, out);
}

// Round 8
// 63.863 us; speedup vs baseline: 1.1475x; 1.1475x over previous
//
#include <hip/hip_runtime.h>

#define TPB 256
#define RPB 8                           // rows per tile (2 tiles per block)
#define SEQ_L 2048
#define CHUNK 256                       // j-chunk width = TPB
#define NCH (SEQ_L / CHUNK)             // 8
#define NBATCH 8
#define NPAIR 128                       // tile pairs (t, 255-t), t in 0..127
#define NBLOCKS (NBATCH * NPAIR)        // 1024
#define NWAVE (TPB / 64)                // 4

static constexpr float kBondTol  = 0.4f;
static constexpr float kClashTol = 1.5f;
static constexpr float kIdeal    = 3.8f;
static constexpr float kEps      = 1e-8f;
static constexpr float kThresh2  = 2.25f;   // 1.5^2: d2 >= this -> relu == 0

__device__ __forceinline__ float wred(float v) {
#pragma unroll
  for (int o = 32; o > 0; o >>= 1) v += __shfl_down(v, o, 64);
  return v;
}

// Every block handles tiles {t, 255-t} (8 rows each). k0(t) + k0(255-t) == 7
// for all t, so EVERY block runs exactly 2 boundary passes + 7 full passes:
// perfectly uniform work with zero assumptions about block->CU scheduling.
// 256-thread blocks, 4 blocks/CU (16 waves/CU) — the empirically best shape.
__global__ __launch_bounds__(TPB, 4) void viol_main(
    const float* __restrict__ pos,    // [B, L, 3]
    const float* __restrict__ mask,   // [B, L]
    float4* __restrict__ partial) {   // [NBLOCKS]: (bv, bm, 2*cv_half, pm)
  __shared__ float4 s[SEQ_L];         // x, y, z, mask  (32 KB)
  __shared__ float  redm[NWAVE];
  __shared__ float  red4[NWAVE][4];

  const int b = blockIdx.x & 7;       // batch -> XCD-pinned L2 reuse
  const int t = blockIdx.x >> 3;      // pair index 0..127
  const int i0A = t << 3;             // low tile rows  [i0A, i0A+8)
  const int i0B = (255 - t) << 3;     // high tile rows
  const int k0A = i0A >> 8;           // 0..3
  const int k0B = i0B >> 8;           // 4..7  (k0A + k0B == 7)

  const float* pb = pos  + (size_t)b * SEQ_L * 3;
  const float* mb = mask + (size_t)b * SEQ_L;

  // ---- stage batch into LDS once, fuse mask-sum into staging ----
  float mpart = 0.f;
#pragma unroll
  for (int it = 0; it < NCH; ++it) {
    int idx = (int)threadIdx.x + (it << 8);
    float x = pb[3 * idx + 0];
    float y = pb[3 * idx + 1];
    float z = pb[3 * idx + 2];
    float m = mb[idx];
    s[idx] = make_float4(x, y, z, m);
    mpart += m;
  }
  mpart = wred(mpart);
  const int wid  = threadIdx.x >> 6;
  const int lane = threadIdx.x & 63;
  if (lane == 0) redm[wid] = mpart;
  __syncthreads();
  const float msum = redm[0] + redm[1] + redm[2] + redm[3];

  float cv = 0.f, pm = 0.f, bv = 0.f, bm = 0.f;

  // ---- two 8-row tiles, sequential; registers reused between tiles ----
  for (int tt = 0; tt < 2; ++tt) {
    const int i0 = tt ? i0B : i0A;
    const int k0 = tt ? k0B : k0A;

    float px[RPB], py[RPB], pz[RPB], pw[RPB], accr[RPB];
#pragma unroll
    for (int q = 0; q < RPB; ++q) {
      float4 p = s[i0 + q];           // broadcast read (conflict-free)
      px[q] = p.x; py[q] = p.y; pz[q] = p.z; pw[q] = p.w;
      accr[q] = 0.f;
    }

    // boundary chunk (contains this tile's diagonal): masked, always-sqrt
    {
      const int j = (int)threadIdx.x + (k0 << 8);
      const float4 pj = s[j];
#pragma unroll
      for (int q = 0; q < RPB; ++q) {
        const int i = i0 + q;
        float dx = pj.x - px[q];
        float dy = pj.y - py[q];
        float dz = pj.z - pz[q];
        float d2 = fmaf(dx, dx, fmaf(dy, dy, dz * dz));
        float dist = __builtin_amdgcn_sqrtf(d2 + kEps);
        float mw = (j > i) ? pj.w : 0.f;        // strict upper triangle
        accr[q] = fmaf(fmaxf(kClashTol - dist, 0.f), mw, accr[q]);
      }
    }

    // full chunks above the tile: d2-only + wave-uniform sqrt skip
#pragma unroll 2
    for (int k = k0 + 1; k < NCH; ++k) {
      float4 pj = s[threadIdx.x + (k << 8)];
      float d2r[RPB];
#pragma unroll
      for (int q = 0; q < RPB; ++q) {
        float dx = pj.x - px[q];
        float dy = pj.y - py[q];
        float dz = pj.z - pz[q];
        d2r[q] = fmaf(dx, dx, fmaf(dy, dy, dz * dz));
      }
      float mv = d2r[0];
#pragma unroll
      for (int q = 1; q < RPB; ++q) mv = fminf(mv, d2r[q]); // fuses to min3
      if (__ballot(mv < kThresh2) != 0ull) {
#pragma unroll
        for (int q = 0; q < RPB; ++q) {
          float dist = __builtin_amdgcn_sqrtf(d2r[q] + kEps);
          accr[q] = fmaf(fmaxf(kClashTol - dist, 0.f), pj.w, accr[q]);
        }
      }
    }

#pragma unroll
    for (int q = 0; q < RPB; ++q) cv = fmaf(pw[q], accr[q], cv);
  }

  // ---- near-diagonal correction (i < j <= i+2) + bond + analytic pm ----
  // 16 rows per block (2 tiles x 8): threads 0..15.
  if (threadIdx.x < 16) {
    const int i = ((threadIdx.x & 8) ? i0B : i0A) + (int)(threadIdx.x & 7);
    const float4 pi = s[i];
    float nv = 0.f;
    const int jhi = (i + 2 > SEQ_L - 1) ? SEQ_L - 1 : i + 2;
    for (int j = i + 1; j <= jhi; ++j) {
      float4 pj = s[j];
      float dx = pj.x - pi.x;
      float dy = pj.y - pi.y;
      float dz = pj.z - pi.z;
      float dist = __builtin_amdgcn_sqrtf(dx * dx + dy * dy + dz * dz + kEps);
      nv += fmaxf(kClashTol - dist, 0.f) * pj.w;
    }
    cv -= pi.w * nv;                  // remove strict-upper near-diagonal

    float nm = 0.f;                   // full |i-j|<=2 window incl. j==i
    const int jlo = (i - 2 < 0) ? 0 : i - 2;
    for (int j = jlo; j <= jhi; ++j) nm += s[j].w;
    pm += pi.w * (msum - nm);         // analytic pair-mask row sum

    if (i < SEQ_L - 1) {
      const float4 pj = s[i + 1];
      float dx = pj.x - pi.x;
      float dy = pj.y - pi.y;
      float dz = pj.z - pi.z;
      float dist = __builtin_amdgcn_sqrtf(dx * dx + dy * dy + dz * dz + kEps);
      float viol = fmaxf(fabsf(dist - kIdeal) - kBondTol, 0.f);
      bv += viol * pi.w * pj.w;
      bm += pi.w * pj.w;
    }
  }

  // ---- block reduction -> ONE plain float4 store per block (no atomics) ----
  bv = wred(bv); bm = wred(bm); cv = wred(cv); pm = wred(pm);
  if (lane == 0) {
    red4[wid][0] = bv; red4[wid][1] = bm;
    red4[wid][2] = cv; red4[wid][3] = pm;
  }
  __syncthreads();
  if (threadIdx.x == 0) {
    float tbv = 0.f, tbm = 0.f, tcv = 0.f, tpm = 0.f;
#pragma unroll
    for (int w = 0; w < NWAVE; ++w) {
      tbv += red4[w][0]; tbm += red4[w][1];
      tcv += red4[w][2]; tpm += red4[w][3];
    }
    // x2: upper triangle -> full ordered sum
    partial[blockIdx.x] = make_float4(tbv, tbm, 2.f * tcv, tpm);
  }
}

__global__ __launch_bounds__(TPB) void viol_reduce(
    const float4* __restrict__ partial, float* __restrict__ out) {
  __shared__ float red4[NWAVE][4];
  float bv = 0.f, bm = 0.f, cv = 0.f, pm = 0.f;
#pragma unroll
  for (int i = threadIdx.x; i < NBLOCKS; i += TPB) {
    float4 p = partial[i];
    bv += p.x; bm += p.y; cv += p.z; pm += p.w;
  }
  bv = wred(bv); bm = wred(bm); cv = wred(cv); pm = wred(pm);
  const int wid  = threadIdx.x >> 6;
  const int lane = threadIdx.x & 63;
  if (lane == 0) {
    red4[wid][0] = bv; red4[wid][1] = bm;
    red4[wid][2] = cv; red4[wid][3] = pm;
  }
  __syncthreads();
  if (threadIdx.x == 0) {
    float tbv = 0.f, tbm = 0.f, tcv = 0.f, tpm = 0.f;
#pragma unroll
    for (int w = 0; w < NWAVE; ++w) {
      tbv += red4[w][0]; tbm += red4[w][1];
      tcv += red4[w][2]; tpm += red4[w][3];
    }
    float bond  = tbv / (tbm + kEps);
    float clash = tcv / (tpm + kEps);
    out[0] = bond;
    out[1] = clash;
    out[2] = bond + clash;
  }
}

extern "C" void kernel_launch(void* const* d_in, const int* in_sizes, int n_in,
                              void* d_out, int out_size, void* d_ws, size_t ws_size,
                              hipStream_t stream) {
  const float* pos  = (const float*)d_in[0];
  const float* mask = (const float*)d_in[1];
  float* out = (float*)d_out;
  float4* partial = (float4*)d_ws;   // 1024 * 16 B = 16 KB scratch

  viol_main<<<dim3(NBLOCKS), dim3(TPB), 0, stream>>>(pos, mask, partial);
  viol_reduce<<<dim3(1), dim3(TPB), 0, stream>>>(partial, out);
}